// Round 2
// baseline (406.700 us; speedup 1.0000x reference)
//
#include <hip/hip_runtime.h>
#include <hip/hip_bf16.h>

// Problem constants (fixed by the reference file)
#define BATCH   8
#define NVERT   50000     // N
#define CIN     32
#define LSP     9
#define KDIM    288       // L*CIN
#define COUT    64
#define MVERT   12500     // num_out_verts
#define NNZ     37500

#define TILE_T  64        // tasks (nnz entries) per block-tile
#define KC      96        // K-chunk = 3 spiral rows
#define NCHUNK  3
#define PADC    100       // KC + 4 pad (float words) to spread LDS banks
#define TPB     586       // tiles per batch = ceil(NNZ/TILE_T)

__global__ __launch_bounds__(256)
void spiral_fused_kernel(const float* __restrict__ x,
                         const float* __restrict__ w,
                         const float* __restrict__ bias,
                         const float* __restrict__ vals,
                         const int* __restrict__ spiral,   // int32 per harness convention
                         const int* __restrict__ rows,     // int32
                         const int* __restrict__ cols,     // int32
                         float* __restrict__ out)
{
    __shared__ float sW[KC * COUT];     // 96*64*4  = 24.0 KB
    __shared__ float sG[TILE_T * PADC]; // 64*100*4 = 25.0 KB  -> 49 KB total

    const int bid  = blockIdx.x;
    const int b    = bid / TPB;
    const int tile = bid - b * TPB;
    const int z0   = tile * TILE_T;
    const int tcnt = min(TILE_T, NNZ - z0);

    const int tid = threadIdx.x;
    const int og  = tid & 15;   // channel group: channels 4*og .. 4*og+3
    const int tg  = tid >> 4;   // task group:    tasks    4*tg .. 4*tg+3

    float acc[4][4];
    #pragma unroll
    for (int i = 0; i < 4; ++i)
        #pragma unroll
        for (int j = 0; j < 4; ++j) acc[i][j] = 0.0f;

    for (int c = 0; c < NCHUNK; ++c) {
        __syncthreads();  // previous chunk's reads done before overwrite

        // ---- stage W chunk: rows [KC*c, KC*c+KC) of (288,64), coalesced f4
        {
            const float4* wsrc = (const float4*)(w + (size_t)c * KC * COUT);
            for (int i = tid; i < KC * COUT / 4; i += 256)
                ((float4*)sW)[i] = wsrc[i];
        }

        // ---- stage gathered activations: 64 tasks x 3 spiral rows
        if (tid < TILE_T * 3) {
            const int t  = tid / 3;
            const int jr = tid - t * 3;          // 0..2 local spiral row
            if (t < tcnt) {
                const int z   = z0 + t;
                const int col = cols[z];
                const int idx = spiral[(size_t)col * LSP + (c * 3 + jr)];
                const float4* src = (const float4*)(x + ((size_t)b * NVERT + idx) * CIN);
                float4* dst = (float4*)(sG + t * PADC + jr * CIN);
                #pragma unroll
                for (int q = 0; q < CIN / 4; ++q) dst[q] = src[q];
            }
            // invalid tail tasks: stale LDS is fine; epilogue skips them
        }
        __syncthreads();

        // ---- compute: per thread 4 tasks x 4 channels over this K-chunk
        #pragma unroll 2
        for (int k4 = 0; k4 < KC / 4; ++k4) {
            const int kk = k4 * 4;
            const float4 wv0 = *(const float4*)(sW + (kk + 0) * COUT + og * 4);
            const float4 wv1 = *(const float4*)(sW + (kk + 1) * COUT + og * 4);
            const float4 wv2 = *(const float4*)(sW + (kk + 2) * COUT + og * 4);
            const float4 wv3 = *(const float4*)(sW + (kk + 3) * COUT + og * 4);
            #pragma unroll
            for (int tt = 0; tt < 4; ++tt) {
                const float4 gv = *(const float4*)(sG + (tg * 4 + tt) * PADC + kk);
                acc[tt][0] += gv.x * wv0.x + gv.y * wv1.x + gv.z * wv2.x + gv.w * wv3.x;
                acc[tt][1] += gv.x * wv0.y + gv.y * wv1.y + gv.z * wv2.y + gv.w * wv3.y;
                acc[tt][2] += gv.x * wv0.z + gv.y * wv1.z + gv.z * wv2.z + gv.w * wv3.z;
                acc[tt][3] += gv.x * wv0.w + gv.y * wv1.w + gv.z * wv2.w + gv.w * wv3.w;
            }
        }
    }

    // ---- epilogue: bias + ELU + scale + scatter-add
    const float4 bv = *(const float4*)(bias + og * 4);
    #pragma unroll
    for (int tt = 0; tt < 4; ++tt) {
        const int t = tg * 4 + tt;
        if (t < tcnt) {
            const int z   = z0 + t;
            const float v = vals[z];
            const int row = rows[z];
            float* dst = out + ((size_t)b * MVERT + row) * COUT + og * 4;
            float y0 = acc[tt][0] + bv.x;
            float y1 = acc[tt][1] + bv.y;
            float y2 = acc[tt][2] + bv.z;
            float y3 = acc[tt][3] + bv.w;
            y0 = (y0 > 0.0f) ? y0 : (__expf(y0) - 1.0f);
            y1 = (y1 > 0.0f) ? y1 : (__expf(y1) - 1.0f);
            y2 = (y2 > 0.0f) ? y2 : (__expf(y2) - 1.0f);
            y3 = (y3 > 0.0f) ? y3 : (__expf(y3) - 1.0f);
            atomicAdd(dst + 0, y0 * v);
            atomicAdd(dst + 1, y1 * v);
            atomicAdd(dst + 2, y2 * v);
            atomicAdd(dst + 3, y3 * v);
        }
    }
}

extern "C" void kernel_launch(void* const* d_in, const int* in_sizes, int n_in,
                              void* d_out, int out_size, void* d_ws, size_t ws_size,
                              hipStream_t stream) {
    const float* x      = (const float*)d_in[0];
    const float* w      = (const float*)d_in[1];
    const float* bias   = (const float*)d_in[2];
    const float* vals   = (const float*)d_in[3];
    const int*   spiral = (const int*)d_in[4];   // int32 (harness converts integer inputs)
    const int*   rows   = (const int*)d_in[5];
    const int*   cols   = (const int*)d_in[6];
    float* out = (float*)d_out;

    // harness poisons d_out with 0xAA before every launch -> zero it
    hipMemsetAsync(d_out, 0, (size_t)out_size * sizeof(float), stream);

    dim3 grid(BATCH * TPB);
    dim3 block(256);
    spiral_fused_kernel<<<grid, block, 0, stream>>>(x, w, bias, vals, spiral, rows, cols, out);
}

// Round 3
// 196.488 us; speedup vs baseline: 2.0699x; 2.0699x over previous
//
#include <hip/hip_runtime.h>

// Problem constants (fixed by the reference file)
#define BATCH   8
#define NVERT   50000     // N
#define CIN     32
#define LSP     9
#define KDIM    288       // L*CIN
#define COUT    64
#define MVERT   12500     // num_out_verts
#define NNZ     37500

#define TILE_T  64        // tasks (nnz entries) per block-tile
#define TPB     586       // ceil(NNZ/TILE_T)
#define PADK    296       // 288 + 8 bf16 pad per task row (breaks pow2 bank stride)
#define NFRAG   2304      // 9 k-steps * 4 col-tiles * 64 lanes (B fragments)

typedef __attribute__((ext_vector_type(8))) short  short8;   // 8 bf16 = 4 VGPR
typedef __attribute__((ext_vector_type(4))) float  floatx4;  // MFMA C/D

// fp32 -> bf16, round-to-nearest-even
static __device__ __forceinline__ unsigned short f2bf(float f) {
    union { float f; unsigned int u; } c; c.f = f;
    unsigned int u = c.u;
    return (unsigned short)((u + 0x7fffu + ((u >> 16) & 1u)) >> 16);
}

// Pack W (288,64) fp32 row-major into MFMA B-fragment order, bf16:
// frag f = (s*4 + g)*64 + lane holds W[s*32 + (lane>>4)*8 + j][g*16 + (lane&15)], j=0..7
__global__ void pack_w_kernel(const float* __restrict__ w, unsigned short* __restrict__ wp) {
    int f = blockIdx.x * blockDim.x + threadIdx.x;
    if (f >= NFRAG) return;
    int s    = f >> 8;
    int g    = (f >> 6) & 3;
    int lane = f & 63;
    int quad = lane >> 4, n = lane & 15;
    int k0   = s * 32 + quad * 8;
    int col  = g * 16 + n;
    unsigned short tmp[8];
    #pragma unroll
    for (int j = 0; j < 8; ++j)
        tmp[j] = f2bf(w[(size_t)(k0 + j) * COUT + col]);
    ((uint4*)wp)[f] = *(uint4*)tmp;
}

__global__ __launch_bounds__(256)
void spiral_mfma_kernel(const float* __restrict__ x,
                        const unsigned short* __restrict__ wp,
                        const float* __restrict__ bias,
                        const float* __restrict__ vals,
                        const int* __restrict__ spiral,
                        const int* __restrict__ rows,
                        const int* __restrict__ cols,
                        float* __restrict__ out)
{
    // 64 tasks x 288 K in bf16, task stride padded to 296 (592 B = 148 dw, 148%32=20
    // -> A-frag reads land <=2-way per bank group, which is free on CDNA4)
    __shared__ unsigned short sG[TILE_T * PADK];   // 37,888 B -> 4 blocks/CU

    const int bid  = blockIdx.x;
    const int b    = bid / TPB;
    const int tile = bid - b * TPB;
    const int z0   = tile * TILE_T;
    const int tcnt = min(TILE_T, NNZ - z0);
    const int tid  = threadIdx.x;

    const float* xb = x + (size_t)b * NVERT * CIN;

    // ---- stage gathered activations: 2304 units = (task, spiral-row, 8-ch group)
    #pragma unroll
    for (int i = 0; i < 9; ++i) {
        int u   = tid + i * 256;
        int t   = u / 36;               // 0..63
        int rem = u - t * 36;
        int r   = rem >> 2;             // spiral row 0..8
        int q   = rem & 3;              // 8-channel group 0..3
        int z   = z0 + t; if (z >= NNZ) z = NNZ - 1;   // tail clamp (epilogue guards)
        int col = cols[z];
        int idx = spiral[col * LSP + r];
        const float4* src = (const float4*)(xb + (size_t)idx * CIN + q * 8);
        float4 a = src[0], c = src[1];
        unsigned short tmp[8];
        tmp[0] = f2bf(a.x); tmp[1] = f2bf(a.y); tmp[2] = f2bf(a.z); tmp[3] = f2bf(a.w);
        tmp[4] = f2bf(c.x); tmp[5] = f2bf(c.y); tmp[6] = f2bf(c.z); tmp[7] = f2bf(c.w);
        *(uint4*)(&sG[t * PADK + r * 32 + q * 8]) = *(uint4*)tmp;
    }
    __syncthreads();

    // ---- MFMA: wave wv computes tasks [16wv,16wv+16) x all 64 channels
    const int wv   = tid >> 6;
    const int lane = tid & 63;
    const int quad = lane >> 4;
    const int m16  = lane & 15;

    const unsigned short* aptr = &sG[(16 * wv + m16) * PADK + quad * 8];

    floatx4 acc[4];
    #pragma unroll
    for (int g = 0; g < 4; ++g) acc[g] = (floatx4){0.f, 0.f, 0.f, 0.f};

    #pragma unroll
    for (int s = 0; s < 9; ++s) {                       // k-step = one spiral row (32 ch)
        short8 af = *(const short8*)(aptr + s * 32);
        #pragma unroll
        for (int g = 0; g < 4; ++g) {                   // 16-channel col tiles
            short8 bf = *(const short8*)(wp + ((size_t)((s * 4 + g) * 64 + lane)) * 8);
            acc[g] = __builtin_amdgcn_mfma_f32_16x16x32_bf16(af, bf, acc[g], 0, 0, 0);
        }
    }

    // ---- epilogue: bias + ELU + scale + scatter-add
    // C layout: col = lane&15 (channel within tile), row = quad*4 + reg (task within 16)
    #pragma unroll
    for (int r = 0; r < 4; ++r) {
        int t = 16 * wv + quad * 4 + r;
        if (t < tcnt) {
            int z     = z0 + t;
            float v   = vals[z];
            int row   = rows[z];
            float* dst = out + ((size_t)b * MVERT + row) * COUT;
            #pragma unroll
            for (int g = 0; g < 4; ++g) {
                int ch  = g * 16 + m16;
                float y = acc[g][r] + bias[ch];
                y = (y > 0.0f) ? y : (__expf(y) - 1.0f);
                atomicAdd(dst + ch, y * v);
            }
        }
    }
}

extern "C" void kernel_launch(void* const* d_in, const int* in_sizes, int n_in,
                              void* d_out, int out_size, void* d_ws, size_t ws_size,
                              hipStream_t stream) {
    const float* x      = (const float*)d_in[0];
    const float* w      = (const float*)d_in[1];
    const float* bias   = (const float*)d_in[2];
    const float* vals   = (const float*)d_in[3];
    const int*   spiral = (const int*)d_in[4];   // int32 per harness convention
    const int*   rows   = (const int*)d_in[5];
    const int*   cols   = (const int*)d_in[6];
    float* out = (float*)d_out;
    unsigned short* wp = (unsigned short*)d_ws;  // 2304*16 B = 36,864 B of scratch

    hipMemsetAsync(d_out, 0, (size_t)out_size * sizeof(float), stream);
    pack_w_kernel<<<9, 256, 0, stream>>>(w, wp);
    spiral_mfma_kernel<<<BATCH * TPB, 256, 0, stream>>>(x, wp, bias, vals,
                                                        spiral, rows, cols, out);
}